// Round 2
// baseline (442.125 us; speedup 1.0000x reference)
//
#include <hip/hip_runtime.h>
#include <stdint.h>

#define DIMN 1024
#define HDN 64
#define SLEN 2048

typedef _Float16 f16;
typedef __attribute__((ext_vector_type(8))) _Float16 f16x8;
typedef __attribute__((ext_vector_type(4))) float f32x4;
typedef __attribute__((ext_vector_type(4))) float f4;

// LDS row stride (elements) for 32/64-wide tiles: 16B-aligned, 2-way-max bank pattern
#define PK 40   // for BK=32 tiles  (40*2=80B... NOT 16B aligned) -- use 48
#define PA 48   // 48*2=96B, multiple of 16
#define PD 72   // for 64-wide tiles: 72*2=144B, multiple of 16

// ---------- transpose + convert weights: WT[n][k] = (f16)W[k][n] ----------
__global__ __launch_bounds__(256) void k_wt(const float* __restrict__ W0, const float* __restrict__ W1,
                                            const float* __restrict__ W2, const float* __restrict__ W3,
                                            f16* __restrict__ WT) {
  __shared__ f16 tile[64][65];
  const float* W = (blockIdx.z == 0) ? W0 : (blockIdx.z == 1) ? W1 : (blockIdx.z == 2) ? W2 : W3;
  f16* T = WT + (size_t)blockIdx.z * DIMN * DIMN;
  int n0 = blockIdx.x * 64, k0 = blockIdx.y * 64;
  int tx = threadIdx.x & 63, ty = threadIdx.x >> 6;
  for (int i = ty; i < 64; i += 4)
    tile[i][tx] = (f16)(W[(size_t)(k0 + i) * DIMN + n0 + tx]);
  __syncthreads();
  for (int i = ty; i < 64; i += 4)
    T[(size_t)(n0 + i) * DIMN + k0 + tx] = tile[tx][i];
}

// ---------- GEMM: C[M,1024] = A[M,1024] @ B, B given as BT[n][k] f16 ----------
// 128x128 tile, BK=32, 4 waves (2x2 of 64x64), 16x16x32 f16 MFMA.
// Plain padded LDS (stride PA elems = 96B): no swizzle, correctness-first.
template <bool AF32, bool OUTF32>
__global__ __launch_bounds__(256) void k_gemm(const void* __restrict__ Ap,
                                              const f16* __restrict__ BT,
                                              void* __restrict__ Cp) {
  __shared__ alignas(16) f16 As[128 * PA];
  __shared__ alignas(16) f16 Bs[128 * PA];
  const int tid = threadIdx.x;
  const int lane = tid & 63, wid = tid >> 6;
  const int wr = wid >> 1, wc = wid & 1;
  const int l15 = lane & 15, lhi = lane >> 4;
  const int m0 = blockIdx.x * 128, n0 = blockIdx.y * 128;
  const int r0 = tid >> 2, c0 = tid & 3;

  f32x4 acc[4][4];
#pragma unroll
  for (int i = 0; i < 4; ++i)
#pragma unroll
    for (int j = 0; j < 4; ++j) { f32x4 z = {0.f, 0.f, 0.f, 0.f}; acc[i][j] = z; }

  for (int kt = 0; kt < DIMN; kt += 32) {
    __syncthreads();
    if (AF32) {
      const float* A = (const float*)Ap;
#pragma unroll
      for (int hh = 0; hh < 2; ++hh) {
        int row = r0 + hh * 64;
        const f4* src = (const f4*)(A + (size_t)(m0 + row) * DIMN + kt + c0 * 8);
        f4 a0 = src[0], a1 = src[1];
        f16x8 vv;
        vv[0] = (f16)a0[0]; vv[1] = (f16)a0[1]; vv[2] = (f16)a0[2]; vv[3] = (f16)a0[3];
        vv[4] = (f16)a1[0]; vv[5] = (f16)a1[1]; vv[6] = (f16)a1[2]; vv[7] = (f16)a1[3];
        *(f16x8*)&As[row * PA + c0 * 8] = vv;
      }
    } else {
      const f16* A = (const f16*)Ap;
#pragma unroll
      for (int hh = 0; hh < 2; ++hh) {
        int row = r0 + hh * 64;
        f16x8 vv = *(const f16x8*)(A + (size_t)(m0 + row) * DIMN + kt + c0 * 8);
        *(f16x8*)&As[row * PA + c0 * 8] = vv;
      }
    }
#pragma unroll
    for (int hh = 0; hh < 2; ++hh) {
      int row = r0 + hh * 64;
      f16x8 vv = *(const f16x8*)(BT + (size_t)(n0 + row) * DIMN + kt + c0 * 8);
      *(f16x8*)&Bs[row * PA + c0 * 8] = vv;
    }
    __syncthreads();
    f16x8 af[4], bb[4];
#pragma unroll
    for (int mf = 0; mf < 4; ++mf) {
      int row = wr * 64 + mf * 16 + l15;
      af[mf] = *(const f16x8*)&As[row * PA + lhi * 8];
    }
#pragma unroll
    for (int nf = 0; nf < 4; ++nf) {
      int row = wc * 64 + nf * 16 + l15;
      bb[nf] = *(const f16x8*)&Bs[row * PA + lhi * 8];
    }
#pragma unroll
    for (int mf = 0; mf < 4; ++mf)
#pragma unroll
      for (int nf = 0; nf < 4; ++nf)
        acc[mf][nf] = __builtin_amdgcn_mfma_f32_16x16x32_f16(af[mf], bb[nf], acc[mf][nf], 0, 0, 0);
  }
#pragma unroll
  for (int mf = 0; mf < 4; ++mf)
#pragma unroll
    for (int r = 0; r < 4; ++r) {
      int row = m0 + wr * 64 + mf * 16 + lhi * 4 + r;
#pragma unroll
      for (int nf = 0; nf < 4; ++nf) {
        int col = n0 + wc * 64 + nf * 16 + l15;
        float x = acc[mf][nf][r];
        if (OUTF32) ((float*)Cp)[(size_t)row * DIMN + col] = x;
        else        ((f16*)Cp)[(size_t)row * DIMN + col] = (f16)x;
      }
    }
}

// ---------- flash attention: block = (128 q-rows, b, h); K/V tiles of 64 keys ----------
// Plain padded LDS (stride PD elems = 144B), scalar V transpose. Correctness-first.
__global__ __launch_bounds__(256) void k_attn(const f16* __restrict__ Qh, const f16* __restrict__ Kh,
                                              const f16* __restrict__ Vh, const float* __restrict__ mask,
                                              f16* __restrict__ att) {
  __shared__ alignas(16) f16 Qs[128 * PD];
  __shared__ alignas(16) f16 Ks[64 * PD];
  __shared__ alignas(16) f16 VTs[64 * PD];  // [d][key]
  __shared__ alignas(16) f16 Ps[128 * PD];
  __shared__ alignas(16) float ml[SLEN];

  const int tid = threadIdx.x;
  const int lane = tid & 63, w = tid >> 6;
  const int l15 = lane & 15, lhi = lane >> 4;
  const int qt = blockIdx.x, bh = blockIdx.y;
  const int b = bh >> 4, h = bh & 15;
  const int q0 = qt * 128;
  const size_t base = (size_t)b * SLEN * DIMN + h * HDN;

  for (int i = tid; i < SLEN / 4; i += 256)
    *(f4*)&ml[i * 4] = *(const f4*)&mask[(size_t)b * SLEN + i * 4];

  for (int s = tid; s < 1024; s += 256) {
    int row = s >> 3, c8 = s & 7;
    *(f16x8*)&Qs[row * PD + c8 * 8] = *(const f16x8*)(Qh + base + (size_t)(q0 + row) * DIMN + c8 * 8);
  }

  f32x4 O[2][4];
  float m_run[2][4], l_run[2][4];
#pragma unroll
  for (int mf = 0; mf < 2; ++mf) {
#pragma unroll
    for (int df = 0; df < 4; ++df) { f32x4 z = {0.f, 0.f, 0.f, 0.f}; O[mf][df] = z; }
#pragma unroll
    for (int r = 0; r < 4; ++r) { m_run[mf][r] = -1e30f; l_run[mf][r] = 0.f; }
  }

  for (int kt = 0; kt < SLEN / 64; ++kt) {
    __syncthreads();
    for (int s = tid; s < 512; s += 256) {
      int key = s >> 3, c8 = s & 7;
      *(f16x8*)&Ks[key * PD + c8 * 8] = *(const f16x8*)(Kh + base + (size_t)(kt * 64 + key) * DIMN + c8 * 8);
    }
    for (int s = tid; s < 512; s += 256) {
      int key = s >> 3, c8 = s & 7;
      f16x8 vv = *(const f16x8*)(Vh + base + (size_t)(kt * 64 + key) * DIMN + c8 * 8);
#pragma unroll
      for (int i = 0; i < 8; ++i)
        VTs[(c8 * 8 + i) * PD + key] = vv[i];
    }
    __syncthreads();

    f32x4 sa[2][4];
#pragma unroll
    for (int mf = 0; mf < 2; ++mf)
#pragma unroll
      for (int nf = 0; nf < 4; ++nf) { f32x4 z = {0.f, 0.f, 0.f, 0.f}; sa[mf][nf] = z; }

#pragma unroll
    for (int ks = 0; ks < 2; ++ks) {
      f16x8 qa[2];
#pragma unroll
      for (int mf = 0; mf < 2; ++mf) {
        int row = w * 32 + mf * 16 + l15;
        qa[mf] = *(const f16x8*)&Qs[row * PD + ks * 32 + lhi * 8];
      }
#pragma unroll
      for (int nf = 0; nf < 4; ++nf) {
        int row = nf * 16 + l15;
        f16x8 kb = *(const f16x8*)&Ks[row * PD + ks * 32 + lhi * 8];
        sa[0][nf] = __builtin_amdgcn_mfma_f32_16x16x32_f16(qa[0], kb, sa[0][nf], 0, 0, 0);
        sa[1][nf] = __builtin_amdgcn_mfma_f32_16x16x32_f16(qa[1], kb, sa[1][nf], 0, 0, 0);
      }
    }

    float mv[4];
#pragma unroll
    for (int nf = 0; nf < 4; ++nf) mv[nf] = ml[kt * 64 + nf * 16 + l15] * 1e9f;
#pragma unroll
    for (int mf = 0; mf < 2; ++mf)
#pragma unroll
      for (int nf = 0; nf < 4; ++nf)
#pragma unroll
        for (int r = 0; r < 4; ++r)
          sa[mf][nf][r] = sa[mf][nf][r] * 0.125f - mv[nf];

#pragma unroll
    for (int mf = 0; mf < 2; ++mf)
#pragma unroll
      for (int r = 0; r < 4; ++r) {
        float t = fmaxf(fmaxf(sa[mf][0][r], sa[mf][1][r]), fmaxf(sa[mf][2][r], sa[mf][3][r]));
        t = fmaxf(t, __shfl_xor(t, 1));
        t = fmaxf(t, __shfl_xor(t, 2));
        t = fmaxf(t, __shfl_xor(t, 4));
        t = fmaxf(t, __shfl_xor(t, 8));
        float newm = fmaxf(m_run[mf][r], t);
        float c = __expf(m_run[mf][r] - newm);
        m_run[mf][r] = newm;
        l_run[mf][r] *= c;
#pragma unroll
        for (int df = 0; df < 4; ++df) O[mf][df][r] *= c;
        int prow = w * 32 + mf * 16 + lhi * 4 + r;
        float ps = 0.f;
#pragma unroll
        for (int nf = 0; nf < 4; ++nf) {
          float p = __expf(sa[mf][nf][r] - newm);
          ps += p;
          Ps[prow * PD + nf * 16 + l15] = (f16)p;
        }
        ps += __shfl_xor(ps, 1);
        ps += __shfl_xor(ps, 2);
        ps += __shfl_xor(ps, 4);
        ps += __shfl_xor(ps, 8);
        l_run[mf][r] += ps;
      }

#pragma unroll
    for (int ks = 0; ks < 2; ++ks) {
      f16x8 pa[2];
#pragma unroll
      for (int mf = 0; mf < 2; ++mf) {
        int row = w * 32 + mf * 16 + l15;
        pa[mf] = *(const f16x8*)&Ps[row * PD + ks * 32 + lhi * 8];
      }
#pragma unroll
      for (int df = 0; df < 4; ++df) {
        int row = df * 16 + l15;
        f16x8 vb = *(const f16x8*)&VTs[row * PD + ks * 32 + lhi * 8];
        O[0][df] = __builtin_amdgcn_mfma_f32_16x16x32_f16(pa[0], vb, O[0][df], 0, 0, 0);
        O[1][df] = __builtin_amdgcn_mfma_f32_16x16x32_f16(pa[1], vb, O[1][df], 0, 0, 0);
      }
    }
  }

#pragma unroll
  for (int mf = 0; mf < 2; ++mf)
#pragma unroll
    for (int r = 0; r < 4; ++r) {
      float inv = 1.0f / l_run[mf][r];
      int row = q0 + w * 32 + mf * 16 + lhi * 4 + r;
#pragma unroll
      for (int df = 0; df < 4; ++df) {
        int col = df * 16 + l15;
        att[base + (size_t)row * DIMN + col] = (f16)(O[mf][df][r] * inv);
      }
    }
}

extern "C" void kernel_launch(void* const* d_in, const int* in_sizes, int n_in,
                              void* d_out, int out_size, void* d_ws, size_t ws_size,
                              hipStream_t stream) {
  const float* q  = (const float*)d_in[0];
  const float* k  = (const float*)d_in[1];
  const float* v  = (const float*)d_in[2];
  const float* mk = (const float*)d_in[3];
  const float* Wq = (const float*)d_in[4];
  const float* Wk = (const float*)d_in[5];
  const float* Wv = (const float*)d_in[6];
  const float* Wo = (const float*)d_in[7];
  char* ws = (char*)d_ws;
  // ws layout: WT(4x2MB=8MB) | Qh 16MB | Kh 16MB | Vh 16MB | att 16MB  => 72MB
  f16* WT  = (f16*)ws;
  f16* Qh  = (f16*)(ws + ((size_t)8 << 20));
  f16* Kh  = (f16*)(ws + ((size_t)24 << 20));
  f16* Vh  = (f16*)(ws + ((size_t)40 << 20));
  f16* att = (f16*)(ws + ((size_t)56 << 20));
  float* out = (float*)d_out;

  k_wt<<<dim3(16, 16, 4), 256, 0, stream>>>(Wq, Wk, Wv, Wo, WT);
  k_gemm<true,  false><<<dim3(64, 8), 256, 0, stream>>>(q, WT, Qh);
  k_gemm<true,  false><<<dim3(64, 8), 256, 0, stream>>>(k, WT + (size_t)DIMN * DIMN, Kh);
  k_gemm<true,  false><<<dim3(64, 8), 256, 0, stream>>>(v, WT + (size_t)2 * DIMN * DIMN, Vh);
  k_attn<<<dim3(16, 64), 256, 0, stream>>>(Qh, Kh, Vh, mk, att);
  k_gemm<false, true><<<dim3(64, 8), 256, 0, stream>>>(att, WT + (size_t)3 * DIMN * DIMN, out);
}

// Round 3
// 317.257 us; speedup vs baseline: 1.3936x; 1.3936x over previous
//
#include <hip/hip_runtime.h>
#include <stdint.h>

#define DIMN 1024
#define HDN 64
#define SLEN 2048

typedef _Float16 f16;
typedef __attribute__((ext_vector_type(8))) _Float16 f16x8;
typedef __attribute__((ext_vector_type(4))) _Float16 f16x4;
typedef __attribute__((ext_vector_type(4))) float f32x4;
typedef __attribute__((ext_vector_type(4))) float f4;

#define PA 48   // GEMM LDS row stride (elems), 96B = 16B-aligned
#define PD 72   // attn LDS row stride (elems), 144B = 16B-aligned, even b128 residues

// ---------- transpose + convert weights: WT[n][k] = (f16)W[k][n] ----------
__global__ __launch_bounds__(256) void k_wt(const float* __restrict__ W0, const float* __restrict__ W1,
                                            const float* __restrict__ W2, const float* __restrict__ W3,
                                            f16* __restrict__ WT) {
  __shared__ f16 tile[64][65];
  const float* W = (blockIdx.z == 0) ? W0 : (blockIdx.z == 1) ? W1 : (blockIdx.z == 2) ? W2 : W3;
  f16* T = WT + (size_t)blockIdx.z * DIMN * DIMN;
  int n0 = blockIdx.x * 64, k0 = blockIdx.y * 64;
  int tx = threadIdx.x & 63, ty = threadIdx.x >> 6;
  for (int i = ty; i < 64; i += 4)
    tile[i][tx] = (f16)(W[(size_t)(k0 + i) * DIMN + n0 + tx]);
  __syncthreads();
  for (int i = ty; i < 64; i += 4)
    T[(size_t)(n0 + i) * DIMN + k0 + tx] = tile[tx][i];
}

// ---------- GEMM: C[M,1024] = A[M,1024] @ B, B given as BT[n][k] f16 ----------
// 128x128 tile, BK=32, 4 waves (2x2 of 64x64), 16x16x32 f16 MFMA.
// OMODE: 0 = f16 row-major out, 1 = f32 row-major out, 2 = f16 VhT[bh][d][s] out
template <bool AF32, int OMODE>
__global__ __launch_bounds__(256) void k_gemm(const void* __restrict__ Ap,
                                              const f16* __restrict__ BT,
                                              void* __restrict__ Cp) {
  __shared__ alignas(16) f16 As[128 * PA];
  __shared__ alignas(16) f16 Bs[128 * PA];
  const int tid = threadIdx.x;
  const int lane = tid & 63, wid = tid >> 6;
  const int wr = wid >> 1, wc = wid & 1;
  const int l15 = lane & 15, lhi = lane >> 4;
  const int m0 = blockIdx.x * 128, n0 = blockIdx.y * 128;
  const int r0 = tid >> 2, c0 = tid & 3;

  f32x4 acc[4][4];
#pragma unroll
  for (int i = 0; i < 4; ++i)
#pragma unroll
    for (int j = 0; j < 4; ++j) { f32x4 z = {0.f, 0.f, 0.f, 0.f}; acc[i][j] = z; }

  for (int kt = 0; kt < DIMN; kt += 32) {
    __syncthreads();
    if (AF32) {
      const float* A = (const float*)Ap;
#pragma unroll
      for (int hh = 0; hh < 2; ++hh) {
        int row = r0 + hh * 64;
        const f4* src = (const f4*)(A + (size_t)(m0 + row) * DIMN + kt + c0 * 8);
        f4 a0 = src[0], a1 = src[1];
        f16x8 vv;
        vv[0] = (f16)a0[0]; vv[1] = (f16)a0[1]; vv[2] = (f16)a0[2]; vv[3] = (f16)a0[3];
        vv[4] = (f16)a1[0]; vv[5] = (f16)a1[1]; vv[6] = (f16)a1[2]; vv[7] = (f16)a1[3];
        *(f16x8*)&As[row * PA + c0 * 8] = vv;
      }
    } else {
      const f16* A = (const f16*)Ap;
#pragma unroll
      for (int hh = 0; hh < 2; ++hh) {
        int row = r0 + hh * 64;
        f16x8 vv = *(const f16x8*)(A + (size_t)(m0 + row) * DIMN + kt + c0 * 8);
        *(f16x8*)&As[row * PA + c0 * 8] = vv;
      }
    }
#pragma unroll
    for (int hh = 0; hh < 2; ++hh) {
      int row = r0 + hh * 64;
      f16x8 vv = *(const f16x8*)(BT + (size_t)(n0 + row) * DIMN + kt + c0 * 8);
      *(f16x8*)&Bs[row * PA + c0 * 8] = vv;
    }
    __syncthreads();
    f16x8 af[4], bb[4];
#pragma unroll
    for (int mf = 0; mf < 4; ++mf) {
      int row = wr * 64 + mf * 16 + l15;
      af[mf] = *(const f16x8*)&As[row * PA + lhi * 8];
    }
#pragma unroll
    for (int nf = 0; nf < 4; ++nf) {
      int row = wc * 64 + nf * 16 + l15;
      bb[nf] = *(const f16x8*)&Bs[row * PA + lhi * 8];
    }
#pragma unroll
    for (int mf = 0; mf < 4; ++mf)
#pragma unroll
      for (int nf = 0; nf < 4; ++nf)
        acc[mf][nf] = __builtin_amdgcn_mfma_f32_16x16x32_f16(af[mf], bb[nf], acc[mf][nf], 0, 0, 0);
  }

  if (OMODE == 2) {
    // store C^T per head: VhT[bh][d][s], s-packed f16x4
    f16* VT = (f16*)Cp;
#pragma unroll
    for (int mf = 0; mf < 4; ++mf) {
      int rowbase = m0 + wr * 64 + mf * 16 + lhi * 4;  // global s row (4 consecutive via r)
      int bq = rowbase >> 11, sl = rowbase & 2047;
#pragma unroll
      for (int nf = 0; nf < 4; ++nf) {
        int col = n0 + wc * 64 + nf * 16 + l15;        // n = h*64+d
        int bh = bq * 16 + (col >> 6), d = col & 63;
        f16x4 pv;
#pragma unroll
        for (int r = 0; r < 4; ++r) pv[r] = (f16)acc[mf][nf][r];
        *(f16x4*)&VT[((size_t)bh * 64 + d) * SLEN + sl] = pv;
      }
    }
  } else {
#pragma unroll
    for (int mf = 0; mf < 4; ++mf)
#pragma unroll
      for (int r = 0; r < 4; ++r) {
        int row = m0 + wr * 64 + mf * 16 + lhi * 4 + r;
#pragma unroll
        for (int nf = 0; nf < 4; ++nf) {
          int col = n0 + wc * 64 + nf * 16 + l15;
          float x = acc[mf][nf][r];
          if (OMODE == 1) ((float*)Cp)[(size_t)row * DIMN + col] = x;
          else            ((f16*)Cp)[(size_t)row * DIMN + col] = (f16)x;
        }
      }
  }
}

// ---------- flash attention, swapped-operand form ----------
// Block = (128 q-rows, one bh). 4 waves x 32 q-rows. K/V tiles of 64 keys.
// S^T = mfma(K, Q): lane l15 = q-col, rows = keys -> softmax reduce = 2 shfl.
// O^T = mfma(V^T, P^T): accumulates O^T[d][q].
__global__ __launch_bounds__(256) void k_attn(const f16* __restrict__ Qh, const f16* __restrict__ Kh,
                                              const f16* __restrict__ VhT, const float* __restrict__ mask,
                                              f16* __restrict__ att) {
  __shared__ alignas(16) f16 Ks[64 * PD];    // [key][d]
  __shared__ alignas(16) f16 VTs[64 * PD];   // [d][key]
  __shared__ alignas(16) f16 Ps[128 * PD];   // [q][key]

  const int tid = threadIdx.x;
  const int lane = tid & 63, w = tid >> 6;
  const int l15 = lane & 15, lhi = lane >> 4;

  // XCD-locality swizzle: ids congruent mod 8 (same XCD) share 8 consecutive bh
  const int id = blockIdx.x;
  const int xcd = id & 7, slot = id >> 3;
  const int qt = slot & 15;
  const int bh = xcd * 8 + (slot >> 4);
  const int b = bh >> 4, h = bh & 15;
  const int q0 = qt * 128;
  const size_t base = (size_t)b * SLEN * DIMN + h * HDN;
  const size_t vtbase = (size_t)bh * 64 * SLEN;

  // Q fragments in registers (B-operand of S^T): lane l15 = q, k = d
  f16x8 qb[2][2];
#pragma unroll
  for (int mf = 0; mf < 2; ++mf)
#pragma unroll
    for (int ks = 0; ks < 2; ++ks)
      qb[mf][ks] = *(const f16x8*)(Qh + base + (size_t)(q0 + w * 32 + mf * 16 + l15) * DIMN + ks * 32 + lhi * 8);

  f32x4 O[2][4];
  float m_run[2] = {-1e30f, -1e30f}, l_run[2] = {0.f, 0.f};
#pragma unroll
  for (int mf = 0; mf < 2; ++mf)
#pragma unroll
    for (int df = 0; df < 4; ++df) { f32x4 z = {0.f, 0.f, 0.f, 0.f}; O[mf][df] = z; }

  for (int kt = 0; kt < SLEN / 64; ++kt) {
    // mask for this key tile: per lane covers keys (nf*16 + lhi*4 + r)
    f4 mkv[4];
#pragma unroll
    for (int nf = 0; nf < 4; ++nf)
      mkv[nf] = *(const f4*)&mask[(size_t)b * SLEN + kt * 64 + nf * 16 + lhi * 4];

    __syncthreads();
    for (int s = tid; s < 512; s += 256) {
      int key = s >> 3, c8 = s & 7;
      *(f16x8*)&Ks[key * PD + c8 * 8] = *(const f16x8*)(Kh + base + (size_t)(kt * 64 + key) * DIMN + c8 * 8);
    }
    for (int s = tid; s < 512; s += 256) {
      int d = s >> 3, c8 = s & 7;
      *(f16x8*)&VTs[d * PD + c8 * 8] = *(const f16x8*)(VhT + vtbase + (size_t)d * SLEN + kt * 64 + c8 * 8);
    }
    __syncthreads();

    // S^T = K x Q^T
    f32x4 sa[2][4];
#pragma unroll
    for (int mf = 0; mf < 2; ++mf)
#pragma unroll
      for (int nf = 0; nf < 4; ++nf) { f32x4 z = {0.f, 0.f, 0.f, 0.f}; sa[mf][nf] = z; }
#pragma unroll
    for (int ks = 0; ks < 2; ++ks) {
#pragma unroll
      for (int nf = 0; nf < 4; ++nf) {
        f16x8 ka = *(const f16x8*)&Ks[(nf * 16 + l15) * PD + ks * 32 + lhi * 8];
        sa[0][nf] = __builtin_amdgcn_mfma_f32_16x16x32_f16(ka, qb[0][ks], sa[0][nf], 0, 0, 0);
        sa[1][nf] = __builtin_amdgcn_mfma_f32_16x16x32_f16(ka, qb[1][ks], sa[1][nf], 0, 0, 0);
      }
    }

    // online softmax (per q = lane column), defer-max threshold 8
#pragma unroll
    for (int mf = 0; mf < 2; ++mf) {
#pragma unroll
      for (int nf = 0; nf < 4; ++nf)
#pragma unroll
        for (int r = 0; r < 4; ++r)
          sa[mf][nf][r] = sa[mf][nf][r] * 0.125f - mkv[nf][r] * 1e9f;
      float t = fmaxf(fmaxf(sa[mf][0][0], sa[mf][0][1]), fmaxf(sa[mf][0][2], sa[mf][0][3]));
#pragma unroll
      for (int nf = 1; nf < 4; ++nf) {
        float a = fmaxf(fmaxf(sa[mf][nf][0], sa[mf][nf][1]), fmaxf(sa[mf][nf][2], sa[mf][nf][3]));
        t = fmaxf(t, a);
      }
      t = fmaxf(t, __shfl_xor(t, 16));
      t = fmaxf(t, __shfl_xor(t, 32));
      if (t > m_run[mf] + 8.0f) {
        float c = __expf(m_run[mf] - t);
        m_run[mf] = t;
        l_run[mf] *= c;
#pragma unroll
        for (int df = 0; df < 4; ++df)
#pragma unroll
          for (int r = 0; r < 4; ++r) O[mf][df][r] *= c;
      }
      float ps = 0.f;
#pragma unroll
      for (int nf = 0; nf < 4; ++nf) {
        f16x4 pv;
#pragma unroll
        for (int r = 0; r < 4; ++r) {
          float p = __expf(sa[mf][nf][r] - m_run[mf]);
          ps += p;
          pv[r] = (f16)p;
        }
        *(f16x4*)&Ps[(w * 32 + mf * 16 + l15) * PD + nf * 16 + lhi * 4] = pv;
      }
      ps += __shfl_xor(ps, 16);
      ps += __shfl_xor(ps, 32);
      l_run[mf] += ps;
    }

    // O^T += V^T x P^T   (Ps rows are intra-wave: lgkmcnt ordering suffices)
#pragma unroll
    for (int ks = 0; ks < 2; ++ks) {
      f16x8 pb[2];
#pragma unroll
      for (int mf = 0; mf < 2; ++mf)
        pb[mf] = *(const f16x8*)&Ps[(w * 32 + mf * 16 + l15) * PD + ks * 32 + lhi * 8];
#pragma unroll
      for (int df = 0; df < 4; ++df) {
        f16x8 va = *(const f16x8*)&VTs[(df * 16 + l15) * PD + ks * 32 + lhi * 8];
        O[0][df] = __builtin_amdgcn_mfma_f32_16x16x32_f16(va, pb[0], O[0][df], 0, 0, 0);
        O[1][df] = __builtin_amdgcn_mfma_f32_16x16x32_f16(va, pb[1], O[1][df], 0, 0, 0);
      }
    }
  }

  // epilogue: O^T[d][q] -> att[q][d], d-packed f16x4
#pragma unroll
  for (int mf = 0; mf < 2; ++mf) {
    float inv = 1.0f / l_run[mf];
    int q = q0 + w * 32 + mf * 16 + l15;
#pragma unroll
    for (int df = 0; df < 4; ++df) {
      f16x4 ov;
#pragma unroll
      for (int r = 0; r < 4; ++r) ov[r] = (f16)(O[mf][df][r] * inv);
      *(f16x4*)(att + base + (size_t)q * DIMN + df * 16 + lhi * 4) = ov;
    }
  }
}

extern "C" void kernel_launch(void* const* d_in, const int* in_sizes, int n_in,
                              void* d_out, int out_size, void* d_ws, size_t ws_size,
                              hipStream_t stream) {
  const float* q  = (const float*)d_in[0];
  const float* k  = (const float*)d_in[1];
  const float* v  = (const float*)d_in[2];
  const float* mk = (const float*)d_in[3];
  const float* Wq = (const float*)d_in[4];
  const float* Wk = (const float*)d_in[5];
  const float* Wv = (const float*)d_in[6];
  const float* Wo = (const float*)d_in[7];
  char* ws = (char*)d_ws;
  // ws layout: WT(4x2MB=8MB) | Qh 16MB | Kh 16MB | VhT 16MB | att 16MB => 72MB
  f16* WT  = (f16*)ws;
  f16* Qh  = (f16*)(ws + ((size_t)8 << 20));
  f16* Kh  = (f16*)(ws + ((size_t)24 << 20));
  f16* VhT = (f16*)(ws + ((size_t)40 << 20));
  f16* att = (f16*)(ws + ((size_t)56 << 20));
  float* out = (float*)d_out;

  k_wt<<<dim3(16, 16, 4), 256, 0, stream>>>(Wq, Wk, Wv, Wo, WT);
  k_gemm<true, 0><<<dim3(64, 8), 256, 0, stream>>>(q, WT, Qh);
  k_gemm<true, 0><<<dim3(64, 8), 256, 0, stream>>>(k, WT + (size_t)DIMN * DIMN, Kh);
  k_gemm<true, 2><<<dim3(64, 8), 256, 0, stream>>>(v, WT + (size_t)2 * DIMN * DIMN, VhT);
  k_attn<<<1024, 256, 0, stream>>>(Qh, Kh, VhT, mk, att);
  k_gemm<false, 1><<<dim3(64, 8), 256, 0, stream>>>(att, WT + (size_t)3 * DIMN * DIMN, out);
}